// Round 15
// baseline (162.778 us; speedup 1.0000x reference)
//
#include <hip/hip_runtime.h>
#include <hip/hip_bf16.h>

#define NROWS 4096
#define NCLS  10000
#define DIM   2048
#define DIMB  1024          // bytes per row in fp4
#define ALPHA_F 10.0f
#define BETA_F  2.0f
#define FP4_SCALE 64.0f
#define INVQ (1.0f / (FP4_SCALE * FP4_SCALE))   // undo scale^2 on dot products
#define NMAIN_BLK 2528      // 79 col-tiles x 32 row-tiles (79*128=10112 >= 10000)
#define NSIM_BLK  528       // 32*33/2 triangle

typedef float f32x4 __attribute__((ext_vector_type(4)));
typedef int   i32x4 __attribute__((ext_vector_type(4)));
typedef int   i32x8 __attribute__((ext_vector_type(8)));

// Merged prep: blocks [0,2048) cast f32 -> fp4 e2m1 (pre-scaled by FP4_SCALE);
// blocks [2048,3072) compute exact fp32 dot(inputs_i, kernel[tgt_i]) (1 wave/row).
__global__ void prep_kernel(const float* __restrict__ X, const float* __restrict__ Kn,
                            const int* __restrict__ tgt,
                            unsigned int* __restrict__ dA, unsigned int* __restrict__ dB,
                            float* __restrict__ dotv, int nA8, int nT8) {
  if (blockIdx.x < 2048) {
    int stride = 2048 * blockDim.x;
    for (int i = blockIdx.x * blockDim.x + threadIdx.x; i < nT8; i += stride) {
      const float* src; unsigned int* dst; int j;
      if (i < nA8) { src = X; dst = dA; j = i; } else { src = Kn; dst = dB; j = i - nA8; }
      float4 a = reinterpret_cast<const float4*>(src)[2 * j];
      float4 b = reinterpret_cast<const float4*>(src)[2 * j + 1];
      float v[8] = {a.x, a.y, a.z, a.w, b.x, b.y, b.z, b.w};
      unsigned int w = 0;
#pragma unroll
      for (int q = 0; q < 8; ++q) {
        float s = v[q] * FP4_SCALE;
        float av = fabsf(s);
        unsigned int code = (unsigned)(av > 0.25f) + (av > 0.75f) + (av > 1.25f)
                          + (av > 1.75f) + (av > 2.5f) + (av > 3.5f) + (av > 5.0f);
        code |= (s < 0.f) ? 8u : 0u;
        w |= code << (4 * q);
      }
      dst[j] = w;
    }
  } else {
    int gtid = (blockIdx.x - 2048) * blockDim.x + threadIdx.x;
    int wave = gtid >> 6;
    int lane = threadIdx.x & 63;
    if (wave >= NROWS) return;
    const float* xr = X + (size_t)wave * DIM;
    const float* kr = Kn + (size_t)tgt[wave] * DIM;
    float s = 0.f;
#pragma unroll
    for (int it = 0; it < DIM / 256; ++it) {
      int k = lane * 4 + it * 256;
      float4 a = *reinterpret_cast<const float4*>(xr + k);
      float4 b = *reinterpret_cast<const float4*>(kr + k);
      s += a.x * b.x + a.y * b.y + a.z * b.z + a.w * b.w;
    }
#pragma unroll
    for (int off = 32; off > 0; off >>= 1) s += __shfl_down(s, off);
    if (lane == 0) dotv[wave] = s;
  }
}

// ---------------------------------------------------------------------------
// Merged 128x128 MX-fp4 (e2m1, unit scales) K=128 MFMA A*B^T with fused
// reduction epilogues; ONE dispatch: main (blocks < 2528) + sim triangle
// (blocks >= 2528). REGISTER-DIET restructure of r14's proven loop:
// 512 threads = 8 waves (2M x 4N), per-wave 64x32 -> acc[4][2] = 32 AGPR,
// frags afr[4]+bfr[2] (24 live VGPR), 2 staging ptrs, est ~78 regs <= 85
// budget at __launch_bounds__(512,6) = 6 waves/SIMD = 3 blocks/CU =
// 24 waves/CU (+50% TLP vs r14's 16 -- the one lever that has always paid
// on this structure). LDS 32KB/block x3 = 96KB. K-loop, dbuf, zero-conflict
// LDS geometry (rows packed 2/128B-line, phys slot8 = logical8 ^ (l&7),
// inverse on gload source, dest linear), hoisted addresses: all r14-proven.
// Spill tripwire: WRITE_SIZE jump => revert (r11 lesson).
// ---------------------------------------------------------------------------

#define AS1 const __attribute__((address_space(1))) void*
#define AS3 __attribute__((address_space(3))) void*

__global__ __launch_bounds__(512, 6)
void gemm_kernel(const unsigned char* __restrict__ A,
                 const unsigned char* __restrict__ Bm,
                 const float* __restrict__ dotv,
                 const int* __restrict__ tgt,
                 float* __restrict__ S1, float* __restrict__ Eacc,
                 float* __restrict__ CNT, float* __restrict__ simAcc) {
  __shared__ unsigned char lds[2 * 16384];   // 2 bufs x (A 8KB + B 8KB)

  const int tid  = threadIdx.x;
  const int lane = tid & 63;
  const int wid  = tid >> 6;       // 0..7
  const int wr   = wid >> 2;       // 0..1  (64-row half)
  const int wc   = wid & 3;        // 0..3  (32-col quarter)
  const int fr   = lane & 15;
  const int kg   = lane >> 4;      // K-block 0..3 (32 elems = 16B) within K=128

  // block role + XCD-aware swizzle (both sub-grids are multiples of 8)
  const int lin = blockIdx.x;
  const bool isMain = lin < NMAIN_BLK;
  int rowTile, colTile, nB;
  const unsigned char* B;
  if (isMain) {
    int swz = (lin & 7) * 316 + (lin >> 3);  // cpx=316; col-major chunks
    colTile = swz / 32;
    rowTile = swz % 32;
    B = Bm; nB = NCLS;
  } else {
    int l2 = lin - NMAIN_BLK;
    int swz = (l2 & 7) * 66 + (l2 >> 3);     // cpx=66; triangle
    int r = 0;
    while ((r + 1) * (r + 2) / 2 <= swz) ++r;
    rowTile = r;
    colTile = swz - r * (r + 1) / 2;
    B = A; nB = NROWS;
  }
  const int rowBase = rowTile * 128;
  const int colBase = colTile * 128;

  // ---- staging precompute (kt-invariant): 512 threads cover the 512 16B
  // slots of each 8KB region; thread t -> line l0 = t>>3, phys slot sp = t&7.
  const int l0  = tid >> 3;                  // 0..63 (128B lines, 2 rows each)
  const int sp  = tid & 7;
  const int lg8 = sp ^ (l0 & 7);             // logical slot
  const int shi = lg8 >> 2, sc16 = lg8 & 3;
  const int rA = rowBase + 2 * l0 + shi;             // A never clamps
  int cB = colBase + 2 * l0 + shi; if (cB > nB - 1) cB = nB - 1;
  const unsigned char* pA = A + (size_t)rA * DIMB + sc16 * 16;
  const unsigned char* pB = B + (size_t)cB * DIMB + sc16 * 16;
  const int dOff = l0 * 128 + sp * 16;       // linear LDS dest

#define STAGE_TILE(BUF, KT)                                                     \
  { int ko_ = (KT) * 64;                                                        \
    unsigned char* d_ = lds + (BUF) * 16384 + dOff;                             \
    __builtin_amdgcn_global_load_lds((AS1)(pA + ko_), (AS3)(d_),        16, 0, 0); \
    __builtin_amdgcn_global_load_lds((AS1)(pB + ko_), (AS3)(d_ + 8192), 16, 0, 0); }

  // ---- fragment-read offsets (kt-invariant) ----
  int offA[4], offB[2];
#pragma unroll
  for (int m2 = 0; m2 < 4; ++m2) {
    int lr = wr * 64 + m2 * 16 + fr;
    int l = lr >> 1;
    offA[m2] = l * 128 + ((((lr & 1) * 4 + kg) ^ (l & 7)) << 4);
  }
#pragma unroll
  for (int n2 = 0; n2 < 2; ++n2) {
    int lc = wc * 32 + n2 * 16 + fr;
    int l = lc >> 1;
    offB[n2] = 8192 + l * 128 + ((((lc & 1) * 4 + kg) ^ (l & 7)) << 4);
  }

  f32x4 acc[4][2];
  const f32x4 zero = {0.f, 0.f, 0.f, 0.f};
#pragma unroll
  for (int m = 0; m < 4; ++m)
#pragma unroll
    for (int n = 0; n < 2; ++n) acc[m][n] = zero;

  // fragment tuples live across the K-loop; zero-halves written ONCE
  i32x8 afr[4], bfr[2];
#pragma unroll
  for (int q = 0; q < 4; ++q)
#pragma unroll
    for (int e = 0; e < 8; ++e) afr[q][e] = 0;
#pragma unroll
  for (int q = 0; q < 2; ++q)
#pragma unroll
    for (int e = 0; e < 8; ++e) bfr[q][e] = 0;

  STAGE_TILE(0, 0);
  __syncthreads();

#pragma unroll 1
  for (int kt = 0; kt < 16; ++kt) {          // 16 K-tiles of 128 elems
    const int buf = kt & 1;
    const int ktn = (kt < 15) ? kt + 1 : 15; // last iter: junk re-stage, never read
    STAGE_TILE(buf ^ 1, ktn);                // overlaps this tile's compute
    const unsigned char* lb = lds + buf * 16384;
#pragma unroll
    for (int n2 = 0; n2 < 2; ++n2) {
      i32x4 v_ = *reinterpret_cast<const i32x4*>(lb + offB[n2]);
      bfr[n2][0] = v_[0]; bfr[n2][1] = v_[1]; bfr[n2][2] = v_[2]; bfr[n2][3] = v_[3];
    }
#pragma unroll
    for (int m2 = 0; m2 < 4; ++m2) {
      i32x4 v_ = *reinterpret_cast<const i32x4*>(lb + offA[m2]);
      afr[m2][0] = v_[0]; afr[m2][1] = v_[1]; afr[m2][2] = v_[2]; afr[m2][3] = v_[3];
    }
    __builtin_amdgcn_s_setprio(1);
#pragma unroll
    for (int m2 = 0; m2 < 4; ++m2)
#pragma unroll
      for (int n2 = 0; n2 < 2; ++n2)
        acc[m2][n2] = __builtin_amdgcn_mfma_scale_f32_16x16x128_f8f6f4(
            afr[m2], bfr[n2], acc[m2][n2], 4, 4, 0, 127, 0, 127);  // fmt 4 = FP4
    __builtin_amdgcn_s_setprio(0);
    __syncthreads();   // publishes buf^1 + protects buf re-stage next iter
  }

  __syncthreads();

  // C/D layout: col-in-frag = fr, row-in-frag = kg*4 + j (shape-determined)
  // global row = rowBase + wr*64 + m*16 + kg*4 + j
  // global col = colBase + wc*32 + n*16 + fr
  if (isMain) {
    float* shPhi = reinterpret_cast<float*>(lds);
    if (tid < 128) shPhi[tid] = dotv[rowBase + tid] - BETA_F;
    __syncthreads();
#pragma unroll
    for (int m = 0; m < 4; ++m) {
#pragma unroll
      for (int j = 0; j < 4; ++j) {
        int rl = wr * 64 + m * 16 + kg * 4 + j;
        float ph = shPhi[rl];
        float s1 = 0.f, ee = 0.f, ct = 0.f;
#pragma unroll
        for (int n = 0; n < 2; ++n) {
          int gcol = colBase + wc * 32 + n * 16 + fr;
          float c = acc[m][n][j] * INVQ;
          c = fminf(fmaxf(c, -1.f), 1.f);
          if (gcol < NCLS) {
            s1 += c;
            ee += __expf(ALPHA_F * c);
            ct += (c > ph) ? 1.f : 0.f;
          }
        }
        // pack ct (integer, <=2/lane -> <=32 summed) with s1 (|sum|<=32):
        // rintf(pk/4096) recovers ct EXACTLY; s1 quantization ~1e-6 on out[3].
        float pk = s1 + ct * 4096.0f;
#pragma unroll
        for (int o = 1; o < 16; o <<= 1) {
          pk += __shfl_xor(pk, o);
          ee += __shfl_xor(ee, o);
        }
        if (fr == 0) {
          int grow = rowBase + rl;
          float ctv = rintf(pk * (1.0f / 4096.0f));
          float s1v = pk - ctv * 4096.0f;
          atomicAdd(&S1[grow], s1v);
          atomicAdd(&Eacc[grow], ee);
          atomicAdd(&CNT[grow], ctv);
        }
      }
    }
  } else {
    const float wgt = (rowTile == colTile) ? 1.f : 2.f;  // symmetry: off-diag x2
    int* shT = reinterpret_cast<int*>(lds);
    float* redbuf = reinterpret_cast<float*>(lds + 4096);
    if (tid < 128) shT[tid] = tgt[rowBase + tid];
    else if (tid < 256) shT[tid] = tgt[colBase + (tid - 128)];
    __syncthreads();
    float ps = 0.f, als = 0.f, pc = 0.f;
#pragma unroll
    for (int m = 0; m < 4; ++m) {
#pragma unroll
      for (int j = 0; j < 4; ++j) {
        int rl = wr * 64 + m * 16 + kg * 4 + j;
        int tr = shT[rl];
#pragma unroll
        for (int n = 0; n < 2; ++n) {
          int cl = wc * 32 + n * 16 + fr;
          float c = acc[m][n][j] * INVQ;   // sim is NOT clipped in the reference
          als += c;
          if (tr == shT[128 + cl]) { ps += c; pc += 1.f; }
        }
      }
    }
#pragma unroll
    for (int o = 1; o < 64; o <<= 1) {
      ps  += __shfl_xor(ps, o);
      als += __shfl_xor(als, o);
      pc  += __shfl_xor(pc, o);
    }
    if (lane == 0) {
      redbuf[wid * 3 + 0] = ps;
      redbuf[wid * 3 + 1] = als;
      redbuf[wid * 3 + 2] = pc;
    }
    __syncthreads();
    if (tid == 0) {
      float p = 0.f, a = 0.f, c2 = 0.f;
      for (int w = 0; w < 8; ++w) {
        p += redbuf[w * 3 + 0];
        a += redbuf[w * 3 + 1];
        c2 += redbuf[w * 3 + 2];
      }
      atomicAdd(&simAcc[0], wgt * p);
      atomicAdd(&simAcc[1], wgt * a);
      atomicAdd(&simAcc[2], wgt * c2);
    }
  }
}

__global__ void finalize_kernel(const float* __restrict__ dotv, const float* __restrict__ S1,
                                const float* __restrict__ Eacc, const float* __restrict__ CNT,
                                const float* __restrict__ simAcc, float* __restrict__ out) {
  __shared__ float sh[5][1024];
  int tid = threadIdx.x;
  float sum_posc = 0.f, sum_s1 = 0.f, loss_sum = 0.f, mask_cnt = 0.f, correct = 0.f;
  for (int i = tid; i < NROWS; i += 1024) {
    float d = dotv[i];
    float posc = fminf(fmaxf(d, -1.f), 1.f);   // pos_cos (clipped target cos)
    float phi = d - BETA_F;
    sum_posc += posc;
    sum_s1 += S1[i];
    float e = Eacc[i] - __expf(ALPHA_F * posc);   // exclude target column
    float cexcl = CNT[i] - 1.f;                   // target always counted (margin = BETA)
    float per = -phi + __logf(e) / ALPHA_F;
    if (cexcl > 0.5f) { loss_sum += per; mask_cnt += 1.f; }
    else correct += 1.f;                          // pred == target iff no non-target col > phi
  }
  sh[0][tid] = sum_posc; sh[1][tid] = sum_s1; sh[2][tid] = loss_sum;
  sh[3][tid] = mask_cnt; sh[4][tid] = correct;
  __syncthreads();
  for (int s = 512; s > 0; s >>= 1) {
    if (tid < s)
      for (int q = 0; q < 5; ++q) sh[q][tid] += sh[q][tid + s];
    __syncthreads();
  }
  if (tid == 0) {
    float posS = sh[0][0], s1S = sh[1][0], lossS = sh[2][0], maskS = sh[3][0], corr = sh[4][0];
    out[0] = lossS / fmaxf(maskS, 1.f);
    out[1] = corr / (float)NROWS;
    out[2] = posS / (float)NROWS;
    out[3] = (s1S - posS) / ((float)NROWS * (float)(NCLS - 1));
    float pos = simAcc[0], all = simAcc[1], pcnt = simAcc[2];
    out[4] = pos / pcnt;
    out[5] = (all - pos) / ((float)NROWS * (float)NROWS - pcnt);
  }
}

extern "C" void kernel_launch(void* const* d_in, const int* in_sizes, int n_in,
                              void* d_out, int out_size, void* d_ws, size_t ws_size,
                              hipStream_t stream) {
  const float* X  = (const float*)d_in[0];   // inputs  [4096][2048] f32
  const int*   tg = (const int*)d_in[1];     // targets [4096] i32
  const float* Kn = (const float*)d_in[2];   // kernel  [10000][2048] f32
  float* out = (float*)d_out;

  char* w = (char*)d_ws;
  unsigned char* f4A = (unsigned char*)w;                  // 4096*1024 B fp4
  unsigned char* f4B = f4A + (size_t)NROWS * DIMB;         // 10000*1024 B fp4
  float* dotv   = (float*)(w + (size_t)NROWS * DIMB + (size_t)NCLS * DIMB);
  float* S1     = dotv + NROWS;
  float* Eacc   = S1 + NROWS;
  float* CNT    = Eacc + NROWS;
  float* simAcc = CNT + NROWS;

  hipMemsetAsync(S1, 0, (3 * NROWS + 4) * sizeof(float), stream);

  const int nA8 = NROWS * DIM / 8, nT8 = nA8 + NCLS * DIM / 8;
  // merged prep: 2048 cast blocks + 1024 gather-dot blocks
  prep_kernel<<<3072, 256, 0, stream>>>(X, Kn, tg, (unsigned int*)f4A,
                                        (unsigned int*)f4B, dotv, nA8, nT8);

  // merged: 2528 main blocks (79x32, cols clamped+masked past 10000)
  //       +  528 sim triangle blocks (off-diag weighted x2)
  gemm_kernel<<<NMAIN_BLK + NSIM_BLK, 512, 0, stream>>>(
      f4A, f4B, dotv, tg, S1, Eacc, CNT, simAcc);

  finalize_kernel<<<1, 1024, 0, stream>>>(dotv, S1, Eacc, CNT, simAcc, out);
}

// Round 16
// 134.672 us; speedup vs baseline: 1.2087x; 1.2087x over previous
//
#include <hip/hip_runtime.h>
#include <hip/hip_bf16.h>

#define NROWS 4096
#define NCLS  10000
#define DIM   2048
#define DIMB  1024          // bytes per row in fp4
#define ALPHA_F 10.0f
#define BETA_F  2.0f
#define FP4_SCALE 64.0f
#define INVQ (1.0f / (FP4_SCALE * FP4_SCALE))   // undo scale^2 on dot products
#define NMAIN_BLK 2528      // 79 col-tiles x 32 row-tiles (79*128=10112 >= 10000)
#define NSIM_BLK  528       // 32*33/2 triangle

typedef float f32x4 __attribute__((ext_vector_type(4)));
typedef int   i32x4 __attribute__((ext_vector_type(4)));
typedef int   i32x8 __attribute__((ext_vector_type(8)));

// Merged prep: blocks [0,2048) cast f32 -> fp4 e2m1 (pre-scaled by FP4_SCALE);
// blocks [2048,3072) compute exact fp32 dot(inputs_i, kernel[tgt_i]) (1 wave/row).
__global__ void prep_kernel(const float* __restrict__ X, const float* __restrict__ Kn,
                            const int* __restrict__ tgt,
                            unsigned int* __restrict__ dA, unsigned int* __restrict__ dB,
                            float* __restrict__ dotv, int nA8, int nT8) {
  if (blockIdx.x < 2048) {
    int stride = 2048 * blockDim.x;
    for (int i = blockIdx.x * blockDim.x + threadIdx.x; i < nT8; i += stride) {
      const float* src; unsigned int* dst; int j;
      if (i < nA8) { src = X; dst = dA; j = i; } else { src = Kn; dst = dB; j = i - nA8; }
      float4 a = reinterpret_cast<const float4*>(src)[2 * j];
      float4 b = reinterpret_cast<const float4*>(src)[2 * j + 1];
      float v[8] = {a.x, a.y, a.z, a.w, b.x, b.y, b.z, b.w};
      unsigned int w = 0;
#pragma unroll
      for (int q = 0; q < 8; ++q) {
        float s = v[q] * FP4_SCALE;
        float av = fabsf(s);
        unsigned int code = (unsigned)(av > 0.25f) + (av > 0.75f) + (av > 1.25f)
                          + (av > 1.75f) + (av > 2.5f) + (av > 3.5f) + (av > 5.0f);
        code |= (s < 0.f) ? 8u : 0u;
        w |= code << (4 * q);
      }
      dst[j] = w;
    }
  } else {
    int gtid = (blockIdx.x - 2048) * blockDim.x + threadIdx.x;
    int wave = gtid >> 6;
    int lane = threadIdx.x & 63;
    if (wave >= NROWS) return;
    const float* xr = X + (size_t)wave * DIM;
    const float* kr = Kn + (size_t)tgt[wave] * DIM;
    float s = 0.f;
#pragma unroll
    for (int it = 0; it < DIM / 256; ++it) {
      int k = lane * 4 + it * 256;
      float4 a = *reinterpret_cast<const float4*>(xr + k);
      float4 b = *reinterpret_cast<const float4*>(kr + k);
      s += a.x * b.x + a.y * b.y + a.z * b.z + a.w * b.w;
    }
#pragma unroll
    for (int off = 32; off > 0; off >>= 1) s += __shfl_down(s, off);
    if (lane == 0) dotv[wave] = s;
  }
}

// ---------------------------------------------------------------------------
// Merged 128x128 MX-fp4 (e2m1, unit scales) K=128 MFMA A*B^T with fused
// reduction epilogues; ONE dispatch: main n x C GEMM (blocks < 2528) +
// lower-triangle sim GEMM (blocks >= 2528). r14-proven local optimum:
// 256 threads = 4 waves (2x2, 64x64 each), BK=128, dbuf 16KB tiles -> 32KB
// LDS, __launch_bounds__(256,4) = 4 blocks/CU. Measured perturbation map:
// (256,5) spills acc (r11); 3-buffer loses a block (r13); 8-wave reg-diet
// raises LDS amplification + widens barrier cone (r15). All regress.
// LDS zero-conflict geometry (measured 0): rows packed 2 per 128B line,
// phys slot8 = logical8 ^ (line&7), inverse pre-applied on gload SOURCE,
// dest linear (rule 21). Staging addresses + read offsets fully hoisted.
// Epilogue packs ct (exact integer at x4096) with s1 -> 8 swizzles/(m,j).
// ---------------------------------------------------------------------------

#define AS1 const __attribute__((address_space(1))) void*
#define AS3 __attribute__((address_space(3))) void*

__global__ __launch_bounds__(256, 4)
void gemm_kernel(const unsigned char* __restrict__ A,
                 const unsigned char* __restrict__ Bm,
                 const float* __restrict__ dotv,
                 const int* __restrict__ tgt,
                 float* __restrict__ S1, float* __restrict__ Eacc,
                 float* __restrict__ CNT, float* __restrict__ simAcc) {
  __shared__ unsigned char lds[2 * 16384];   // 2 bufs x (A 8KB + B 8KB)

  const int tid  = threadIdx.x;
  const int lane = tid & 63;
  const int wid  = tid >> 6;
  const int wr   = wid >> 1;       // 0..1
  const int wc   = wid & 1;        // 0..1
  const int fr   = lane & 15;
  const int kg   = lane >> 4;      // K-block 0..3 (32 elems = 16B) within K=128

  // block role + XCD-aware swizzle (both sub-grids are multiples of 8)
  const int lin = blockIdx.x;
  const bool isMain = lin < NMAIN_BLK;
  int rowTile, colTile, nB;
  const unsigned char* B;
  if (isMain) {
    int swz = (lin & 7) * 316 + (lin >> 3);  // cpx=316; col-major chunks
    colTile = swz / 32;                      // ~10 col-panels per XCD
    rowTile = swz % 32;
    B = Bm; nB = NCLS;
  } else {
    int l2 = lin - NMAIN_BLK;
    int swz = (l2 & 7) * 66 + (l2 >> 3);     // cpx=66; triangle
    int r = 0;
    while ((r + 1) * (r + 2) / 2 <= swz) ++r;
    rowTile = r;
    colTile = swz - r * (r + 1) / 2;
    B = A; nB = NROWS;
  }
  const int rowBase = rowTile * 128;
  const int colBase = colTile * 128;

  // ---- staging precompute (kt-invariant) ----
  const int l0  = tid >> 3;                  // line within 32-line quarter
  const int sp  = tid & 7;                   // phys slot
  const int lg8 = sp ^ (l0 & 7);             // logical slot
  const int shi = lg8 >> 2, sc16 = lg8 & 3;
  const int rA0 = rowBase + 2 * l0 + shi;            // A never clamps
  const int rA1 = rA0 + 64;
  int cB0 = colBase + 2 * l0 + shi;      if (cB0 > nB - 1) cB0 = nB - 1;
  int cB1 = colBase + 64 + 2 * l0 + shi; if (cB1 > nB - 1) cB1 = nB - 1;
  const unsigned char* pA0 = A + (size_t)rA0 * DIMB + sc16 * 16;
  const unsigned char* pA1 = A + (size_t)rA1 * DIMB + sc16 * 16;
  const unsigned char* pB0 = B + (size_t)cB0 * DIMB + sc16 * 16;
  const unsigned char* pB1 = B + (size_t)cB1 * DIMB + sc16 * 16;
  const int dOff = l0 * 128 + sp * 16;       // linear LDS dest (quarter base added)

#define STAGE_TILE(BUF, KT)                                                     \
  { int ko_ = (KT) * 64;                                                        \
    unsigned char* d_ = lds + (BUF) * 16384 + dOff;                             \
    __builtin_amdgcn_global_load_lds((AS1)(pA0 + ko_), (AS3)(d_),          16, 0, 0); \
    __builtin_amdgcn_global_load_lds((AS1)(pA1 + ko_), (AS3)(d_ + 4096),   16, 0, 0); \
    __builtin_amdgcn_global_load_lds((AS1)(pB0 + ko_), (AS3)(d_ + 8192),   16, 0, 0); \
    __builtin_amdgcn_global_load_lds((AS1)(pB1 + ko_), (AS3)(d_ + 12288),  16, 0, 0); }

  // ---- fragment-read offsets (kt-invariant, fully unrolled -> registers) ----
  int offA[4], offB[4];
#pragma unroll
  for (int m2 = 0; m2 < 4; ++m2) {
    int lr = wr * 64 + m2 * 16 + fr;
    int l = lr >> 1;
    offA[m2] = l * 128 + ((((lr & 1) * 4 + kg) ^ (l & 7)) << 4);
  }
#pragma unroll
  for (int n2 = 0; n2 < 4; ++n2) {
    int lc = wc * 64 + n2 * 16 + fr;
    int l = lc >> 1;
    offB[n2] = 8192 + l * 128 + ((((lc & 1) * 4 + kg) ^ (l & 7)) << 4);
  }

  f32x4 acc[4][4];
  const f32x4 zero = {0.f, 0.f, 0.f, 0.f};
#pragma unroll
  for (int m = 0; m < 4; ++m)
#pragma unroll
    for (int n = 0; n < 4; ++n) acc[m][n] = zero;

  // fragment tuples live across the K-loop; zero-halves written ONCE
  i32x8 afr[4], bfr[4];
#pragma unroll
  for (int q = 0; q < 4; ++q) {
#pragma unroll
    for (int e = 0; e < 8; ++e) { afr[q][e] = 0; bfr[q][e] = 0; }
  }

  STAGE_TILE(0, 0);
  __syncthreads();

#pragma unroll 1
  for (int kt = 0; kt < 16; ++kt) {          // 16 K-tiles of 128 elems
    const int buf = kt & 1;
    const int ktn = (kt < 15) ? kt + 1 : 15; // last iter: junk re-stage, never read
    STAGE_TILE(buf ^ 1, ktn);                // overlaps this tile's compute
    const unsigned char* lb = lds + buf * 16384;
#pragma unroll
    for (int m2 = 0; m2 < 4; ++m2) {
      i32x4 v_ = *reinterpret_cast<const i32x4*>(lb + offA[m2]);
      afr[m2][0] = v_[0]; afr[m2][1] = v_[1]; afr[m2][2] = v_[2]; afr[m2][3] = v_[3];
    }
#pragma unroll
    for (int n2 = 0; n2 < 4; ++n2) {
      i32x4 v_ = *reinterpret_cast<const i32x4*>(lb + offB[n2]);
      bfr[n2][0] = v_[0]; bfr[n2][1] = v_[1]; bfr[n2][2] = v_[2]; bfr[n2][3] = v_[3];
    }
    __builtin_amdgcn_s_setprio(1);
#pragma unroll
    for (int m2 = 0; m2 < 4; ++m2)
#pragma unroll
      for (int n2 = 0; n2 < 4; ++n2)
        acc[m2][n2] = __builtin_amdgcn_mfma_scale_f32_16x16x128_f8f6f4(
            afr[m2], bfr[n2], acc[m2][n2], 4, 4, 0, 127, 0, 127);  // fmt 4 = FP4
    __builtin_amdgcn_s_setprio(0);
    __syncthreads();   // publishes buf^1 + protects buf re-stage next iter
  }

  __syncthreads();

  // C/D layout: col-in-frag = fr, row-in-frag = kg*4 + j (shape-determined)
  // global row = rowBase + wr*64 + m*16 + kg*4 + j
  // global col = colBase + wc*64 + n*16 + fr
  if (isMain) {
    float* shPhi = reinterpret_cast<float*>(lds);
    if (tid < 128) shPhi[tid] = dotv[rowBase + tid] - BETA_F;
    __syncthreads();
#pragma unroll
    for (int m = 0; m < 4; ++m) {
#pragma unroll
      for (int j = 0; j < 4; ++j) {
        int rl = wr * 64 + m * 16 + kg * 4 + j;
        float ph = shPhi[rl];
        float s1 = 0.f, ee = 0.f, ct = 0.f;
#pragma unroll
        for (int n = 0; n < 4; ++n) {
          int gcol = colBase + wc * 64 + n * 16 + fr;
          float c = acc[m][n][j] * INVQ;
          c = fminf(fmaxf(c, -1.f), 1.f);
          if (gcol < NCLS) {
            s1 += c;
            ee += __expf(ALPHA_F * c);
            ct += (c > ph) ? 1.f : 0.f;
          }
        }
        // pack ct (integer, <=4/lane -> <=64 summed) with s1 (|.|<=4/lane):
        // pk = s1 + 4096*ct; rintf(pk/4096) recovers ct EXACTLY (|s1sum|<=64
        // << 2048); s1 quantization <=2^-5 -> ~1e-6 on out[3].
        float pk = s1 + ct * 4096.0f;
#pragma unroll
        for (int o = 1; o < 16; o <<= 1) {
          pk += __shfl_xor(pk, o);
          ee += __shfl_xor(ee, o);
        }
        if (fr == 0) {
          int grow = rowBase + rl;
          float ctv = rintf(pk * (1.0f / 4096.0f));
          float s1v = pk - ctv * 4096.0f;
          atomicAdd(&S1[grow], s1v);
          atomicAdd(&Eacc[grow], ee);
          atomicAdd(&CNT[grow], ctv);
        }
      }
    }
  } else {
    const float wgt = (rowTile == colTile) ? 1.f : 2.f;  // symmetry: off-diag x2
    int* shT = reinterpret_cast<int*>(lds);
    float* redbuf = reinterpret_cast<float*>(lds + 4096);
    if (tid < 128) shT[tid] = tgt[rowBase + tid];
    else if (tid < 256) shT[tid] = tgt[colBase + (tid - 128)];
    __syncthreads();
    float ps = 0.f, als = 0.f, pc = 0.f;
#pragma unroll
    for (int m = 0; m < 4; ++m) {
#pragma unroll
      for (int j = 0; j < 4; ++j) {
        int rl = wr * 64 + m * 16 + kg * 4 + j;
        int tr = shT[rl];
#pragma unroll
        for (int n = 0; n < 4; ++n) {
          int cl = wc * 64 + n * 16 + fr;
          float c = acc[m][n][j] * INVQ;   // sim is NOT clipped in the reference
          als += c;
          if (tr == shT[128 + cl]) { ps += c; pc += 1.f; }
        }
      }
    }
#pragma unroll
    for (int o = 1; o < 64; o <<= 1) {
      ps  += __shfl_xor(ps, o);
      als += __shfl_xor(als, o);
      pc  += __shfl_xor(pc, o);
    }
    if (lane == 0) {
      redbuf[wid * 3 + 0] = ps;
      redbuf[wid * 3 + 1] = als;
      redbuf[wid * 3 + 2] = pc;
    }
    __syncthreads();
    if (tid == 0) {
      float p = 0.f, a = 0.f, c2 = 0.f;
      for (int w = 0; w < 4; ++w) {
        p += redbuf[w * 3 + 0];
        a += redbuf[w * 3 + 1];
        c2 += redbuf[w * 3 + 2];
      }
      atomicAdd(&simAcc[0], wgt * p);
      atomicAdd(&simAcc[1], wgt * a);
      atomicAdd(&simAcc[2], wgt * c2);
    }
  }
}

__global__ void finalize_kernel(const float* __restrict__ dotv, const float* __restrict__ S1,
                                const float* __restrict__ Eacc, const float* __restrict__ CNT,
                                const float* __restrict__ simAcc, float* __restrict__ out) {
  __shared__ float sh[5][1024];
  int tid = threadIdx.x;
  float sum_posc = 0.f, sum_s1 = 0.f, loss_sum = 0.f, mask_cnt = 0.f, correct = 0.f;
  for (int i = tid; i < NROWS; i += 1024) {
    float d = dotv[i];
    float posc = fminf(fmaxf(d, -1.f), 1.f);   // pos_cos (clipped target cos)
    float phi = d - BETA_F;
    sum_posc += posc;
    sum_s1 += S1[i];
    float e = Eacc[i] - __expf(ALPHA_F * posc);   // exclude target column
    float cexcl = CNT[i] - 1.f;                   // target always counted (margin = BETA)
    float per = -phi + __logf(e) / ALPHA_F;
    if (cexcl > 0.5f) { loss_sum += per; mask_cnt += 1.f; }
    else correct += 1.f;                          // pred == target iff no non-target col > phi
  }
  sh[0][tid] = sum_posc; sh[1][tid] = sum_s1; sh[2][tid] = loss_sum;
  sh[3][tid] = mask_cnt; sh[4][tid] = correct;
  __syncthreads();
  for (int s = 512; s > 0; s >>= 1) {
    if (tid < s)
      for (int q = 0; q < 5; ++q) sh[q][tid] += sh[q][tid + s];
    __syncthreads();
  }
  if (tid == 0) {
    float posS = sh[0][0], s1S = sh[1][0], lossS = sh[2][0], maskS = sh[3][0], corr = sh[4][0];
    out[0] = lossS / fmaxf(maskS, 1.f);
    out[1] = corr / (float)NROWS;
    out[2] = posS / (float)NROWS;
    out[3] = (s1S - posS) / ((float)NROWS * (float)(NCLS - 1));
    float pos = simAcc[0], all = simAcc[1], pcnt = simAcc[2];
    out[4] = pos / pcnt;
    out[5] = (all - pos) / ((float)NROWS * (float)NROWS - pcnt);
  }
}

extern "C" void kernel_launch(void* const* d_in, const int* in_sizes, int n_in,
                              void* d_out, int out_size, void* d_ws, size_t ws_size,
                              hipStream_t stream) {
  const float* X  = (const float*)d_in[0];   // inputs  [4096][2048] f32
  const int*   tg = (const int*)d_in[1];     // targets [4096] i32
  const float* Kn = (const float*)d_in[2];   // kernel  [10000][2048] f32
  float* out = (float*)d_out;

  char* w = (char*)d_ws;
  unsigned char* f4A = (unsigned char*)w;                  // 4096*1024 B fp4
  unsigned char* f4B = f4A + (size_t)NROWS * DIMB;         // 10000*1024 B fp4
  float* dotv   = (float*)(w + (size_t)NROWS * DIMB + (size_t)NCLS * DIMB);
  float* S1     = dotv + NROWS;
  float* Eacc   = S1 + NROWS;
  float* CNT    = Eacc + NROWS;
  float* simAcc = CNT + NROWS;

  hipMemsetAsync(S1, 0, (3 * NROWS + 4) * sizeof(float), stream);

  const int nA8 = NROWS * DIM / 8, nT8 = nA8 + NCLS * DIM / 8;
  // merged prep: 2048 cast blocks + 1024 gather-dot blocks
  prep_kernel<<<3072, 256, 0, stream>>>(X, Kn, tg, (unsigned int*)f4A,
                                        (unsigned int*)f4B, dotv, nA8, nT8);

  // merged: 2528 main blocks (79x32, cols clamped+masked past 10000)
  //       +  528 sim triangle blocks (off-diag weighted x2)
  gemm_kernel<<<NMAIN_BLK + NSIM_BLK, 256, 0, stream>>>(
      f4A, f4B, dotv, tg, S1, Eacc, CNT, simAcc);

  finalize_kernel<<<1, 1024, 0, stream>>>(dotv, S1, Eacc, CNT, simAcc, out);
}